// Round 1
// baseline (404.505 us; speedup 1.0000x reference)
//
#include <hip/hip_runtime.h>
#include <stdint.h>

typedef __attribute__((ext_vector_type(4))) float f32x4;
typedef __attribute__((ext_vector_type(8))) short s16x8;

typedef const __attribute__((address_space(1))) void* gas_ptr;
typedef __attribute__((address_space(3))) void* las_ptr;

__device__ __forceinline__ unsigned short f2b(float f) {
    // fp32 -> bf16 round-to-nearest-even (finite values)
    union { float f; unsigned u; } v; v.f = f;
    unsigned r = v.u + 0x7fffu + ((v.u >> 16) & 1u);
    return (unsigned short)(r >> 16);
}

// ---------------------------------------------------------------------------
// cast two fp32 arrays to bf16 (A_s, A_t)
__global__ void cast2_bf16_k(const float* __restrict__ a, unsigned short* __restrict__ da,
                             const float* __restrict__ b, unsigned short* __restrict__ db,
                             int n4) {
    int i = blockIdx.x * blockDim.x + threadIdx.x;
    int stride = gridDim.x * blockDim.x;
    for (; i < n4; i += stride) {
        float4 va = ((const float4*)a)[i];
        ushort4 pa; pa.x = f2b(va.x); pa.y = f2b(va.y); pa.z = f2b(va.z); pa.w = f2b(va.w);
        ((ushort4*)da)[i] = pa;
        float4 vb = ((const float4*)b)[i];
        ushort4 pb; pb.x = f2b(vb.x); pb.y = f2b(vb.y); pb.z = f2b(vb.z); pb.w = f2b(vb.w);
        ((ushort4*)db)[i] = pb;
    }
}

__global__ void cast_f32_bf16_k(const float* __restrict__ s, unsigned short* __restrict__ d, int n4) {
    int i = blockIdx.x * blockDim.x + threadIdx.x;
    int stride = gridDim.x * blockDim.x;
    for (; i < n4; i += stride) {
        float4 v = ((const float4*)s)[i];
        ushort4 p; p.x = f2b(v.x); p.y = f2b(v.y); p.z = f2b(v.z); p.w = f2b(v.w);
        ((ushort4*)d)[i] = p;
    }
}

// dst[C x R] = bf16(src[R x C]^T); R,C multiples of 32
__global__ void transpose_cast_k(const float* __restrict__ src, unsigned short* __restrict__ dst,
                                 int R, int C) {
    __shared__ float tile[32][33];
    int c0 = blockIdx.x * 32, r0 = blockIdx.y * 32;
    int tx = threadIdx.x & 31, ty = threadIdx.x >> 5;
    #pragma unroll
    for (int rr = ty; rr < 32; rr += 8)
        tile[rr][tx] = src[(size_t)(r0 + rr) * C + c0 + tx];
    __syncthreads();
    #pragma unroll
    for (int rr = ty; rr < 32; rr += 8)
        dst[(size_t)(c0 + rr) * R + r0 + tx] = f2b(tile[tx][rr]);
}

// ---------------------------------------------------------------------------
// NT bf16 GEMM: C[m,n] = sum_k A[m,k] * B[n,k]   (A:[M x K] rm, B:[N x K] rm)
// 256 threads = 4 waves (2x2). Wave tile = (FM*16) x (FN*16).
// BM = 32*FM, BN = 32*FN. BK = 32. mfma_f32_16x16x32_bf16.
// Epilogues:
enum { EP_ATOMIC = 0,          // atomicAdd fp32 into Cf (split-K; Cf pre-zeroed)
       EP_BF16 = 1,            // bf16 row-major to Cb
       EP_RELU_T = 2,          // relu, bf16 transposed store to Ct (ldct)
       EP_RELU_RM_TFOLD = 3,   // relu, bf16 rm to Cb + folded-transpose to Ct
       EP_EXP = 4,             // exp, fp32 rm to Cf AND bf16 rm to Cb
       EP_F32 = 5 };           // fp32 rm to Cf

template<int BM, int BN, int FM, int FN, int EPI, bool DUAL>
__global__ void __launch_bounds__(256)
gemm_nt(const unsigned short* __restrict__ A, const unsigned short* __restrict__ A2,
        const unsigned short* __restrict__ B, const unsigned short* __restrict__ B2,
        int Mhalf, int lda, int ldb, int kchunk,
        float* __restrict__ Cf, unsigned short* __restrict__ Cb,
        unsigned short* __restrict__ Ct, int ldc, int ldct)
{
    static_assert(BM == 32 * FM && BN == 32 * FN, "tile shape");
    __shared__ __align__(16) short As[BM * 32];
    __shared__ __align__(16) short Bs[BN * 32];

    const int t = threadIdx.x;
    const int lane = t & 63;
    const int w = t >> 6;
    const int wr = w >> 1, wc = w & 1;
    const int m0 = blockIdx.x * BM;
    const int n0 = blockIdx.y * BN;
    const int k0 = blockIdx.z * kchunk;

    const unsigned short* Ap = A;
    const unsigned short* Bp = B;
    int am0 = m0;
    if (DUAL && m0 >= Mhalf) { Ap = A2; Bp = B2; am0 = m0 - Mhalf; }

    f32x4 acc[FM][FN];
    #pragma unroll
    for (int i = 0; i < FM; i++)
        #pragma unroll
        for (int j = 0; j < FN; j++) acc[i][j] = (f32x4){0.f, 0.f, 0.f, 0.f};

    constexpr int AIT = (BM * 64) / 4096;   // staging iters (256 thr x 16B)
    constexpr int BIT = (BN * 64) / 4096;
    const int KT = kchunk >> 5;

    const int mrow = lane & 15;
    const int q8 = (lane >> 4) << 3;

    for (int kt = 0; kt < KT; ++kt) {
        const int kk = k0 + (kt << 5);
        #pragma unroll
        for (int it = 0; it < AIT; ++it) {
            int idx = it * 256 + t;
            const unsigned short* g = Ap + (size_t)(am0 + (idx >> 2)) * lda + kk + ((idx & 3) << 3);
            __builtin_amdgcn_global_load_lds((gas_ptr)g, (las_ptr)(As + idx * 8), 16, 0, 0);
        }
        #pragma unroll
        for (int it = 0; it < BIT; ++it) {
            int idx = it * 256 + t;
            const unsigned short* g = Bp + (size_t)(n0 + (idx >> 2)) * ldb + kk + ((idx & 3) << 3);
            __builtin_amdgcn_global_load_lds((gas_ptr)g, (las_ptr)(Bs + idx * 8), 16, 0, 0);
        }
        __syncthreads();

        s16x8 af[FM], bfr[FN];
        #pragma unroll
        for (int i = 0; i < FM; i++)
            af[i] = *(const s16x8*)(const void*)(As + (wr * FM * 16 + i * 16 + mrow) * 32 + q8);
        #pragma unroll
        for (int j = 0; j < FN; j++)
            bfr[j] = *(const s16x8*)(const void*)(Bs + (wc * FN * 16 + j * 16 + mrow) * 32 + q8);
        #pragma unroll
        for (int i = 0; i < FM; i++)
            #pragma unroll
            for (int j = 0; j < FN; j++)
                acc[i][j] = __builtin_amdgcn_mfma_f32_16x16x32_bf16(af[i], bfr[j], acc[i][j], 0, 0, 0);
        __syncthreads();
    }

    // epilogue: D frag mapping col = lane&15, row = (lane>>4)*4 + reg
    const int cn = lane & 15;
    const int q4 = (lane >> 4) << 2;
    #pragma unroll
    for (int i = 0; i < FM; i++) {
        const int mb = m0 + wr * FM * 16 + i * 16 + q4;
        #pragma unroll
        for (int j = 0; j < FN; j++) {
            const int nn = n0 + wc * FN * 16 + j * 16 + cn;
            if constexpr (EPI == EP_ATOMIC) {
                #pragma unroll
                for (int r = 0; r < 4; r++)
                    atomicAdd(Cf + (size_t)(mb + r) * ldc + nn, acc[i][j][r]);
            } else if constexpr (EPI == EP_F32) {
                #pragma unroll
                for (int r = 0; r < 4; r++)
                    Cf[(size_t)(mb + r) * ldc + nn] = acc[i][j][r];
            } else if constexpr (EPI == EP_BF16) {
                #pragma unroll
                for (int r = 0; r < 4; r++)
                    Cb[(size_t)(mb + r) * ldc + nn] = f2b(acc[i][j][r]);
            } else if constexpr (EPI == EP_RELU_T) {
                ushort4 p;
                p.x = f2b(fmaxf(acc[i][j][0], 0.f));
                p.y = f2b(fmaxf(acc[i][j][1], 0.f));
                p.z = f2b(fmaxf(acc[i][j][2], 0.f));
                p.w = f2b(fmaxf(acc[i][j][3], 0.f));
                *(ushort4*)(void*)(Ct + (size_t)nn * ldct + mb) = p;
            } else if constexpr (EPI == EP_RELU_RM_TFOLD) {
                ushort4 p;
                p.x = f2b(fmaxf(acc[i][j][0], 0.f));
                p.y = f2b(fmaxf(acc[i][j][1], 0.f));
                p.z = f2b(fmaxf(acc[i][j][2], 0.f));
                p.w = f2b(fmaxf(acc[i][j][3], 0.f));
                Cb[(size_t)(mb + 0) * ldc + nn] = p.x;
                Cb[(size_t)(mb + 1) * ldc + nn] = p.y;
                Cb[(size_t)(mb + 2) * ldc + nn] = p.z;
                Cb[(size_t)(mb + 3) * ldc + nn] = p.w;
                const int trow = nn + ((mb >> 12) << 7);   // +128 for the t-half (m>=4096)
                *(ushort4*)(void*)(Ct + (size_t)trow * ldct + (mb & 4095)) = p;
            } else if constexpr (EPI == EP_EXP) {
                #pragma unroll
                for (int r = 0; r < 4; r++) {
                    float v = __expf(acc[i][j][r]);
                    Cf[(size_t)(mb + r) * ldc + nn] = v;
                    Cb[(size_t)(mb + r) * ldc + nn] = f2b(v);
                }
            }
        }
    }
}

// ---------------------------------------------------------------------------
extern "C" void kernel_launch(void* const* d_in, const int* in_sizes, int n_in,
                              void* d_out, int out_size, void* d_ws, size_t ws_size,
                              hipStream_t stream) {
    const int N = 4096;
    const float* A_s = (const float*)d_in[0];
    const float* X_s = (const float*)d_in[1];
    const float* A_t = (const float*)d_in[2];
    const float* X_t = (const float*)d_in[3];
    const float* W1  = (const float*)d_in[4];
    const float* W2  = (const float*)d_in[5];
    const float* W3  = (const float*)d_in[6];
    const float* W4  = (const float*)d_in[7];

    float* out   = (float*)d_out;
    float* out_s = out;
    float* out_t = out + (size_t)N * 128;
    float* S_out = out + (size_t)2 * N * 128;

    char* ws = (char*)d_ws;
    // workspace layout (bytes); aggressive aliasing to stay < ~88 MB
    unsigned short* Asb = (unsigned short*)(ws + 0);          // 32 MB [4096x4096] bf16
    unsigned short* Atb = (unsigned short*)(ws + 33554432);   // 32 MB
    unsigned short* Sb  = Asb;                                // alias: S bf16 (A's dead by then)
    char* pool = ws + 67108864;
    unsigned short* XsT = (unsigned short*)(pool + 0);        // 2 MB [256x4096]
    unsigned short* XtT = (unsigned short*)(pool + 2097152);  // 2 MB
    unsigned short* W1t = (unsigned short*)(pool + 4194304);  // 64 KB [128x256]
    unsigned short* W2t = (unsigned short*)(pool + 4259840);  // 32 KB [128x128]
    unsigned short* W3t = (unsigned short*)(pool + 4292608);  // 32 KB
    unsigned short* W4t = (unsigned short*)(pool + 4325376);  // 32 KB
    float*          T1f = (float*)(pool + 4358144);           // 8 MB [8192x256] f32
    unsigned short* T1b = (unsigned short*)(pool + 12746752); // 4 MB [8192x256] bf16
    unsigned short* XcatT = (unsigned short*)(pool + 16941056); // 2 MB [256x4096]
    unsigned short* Pb  = (unsigned short*)(pool + 19038208); // 1 MB [4096x128]
    // aliases (lifetimes disjoint):
    unsigned short* Xcat1T = XsT;                         // 2 MB [128x8192] (XsT dead after G1)
    float* T2f   = T1f;                                   // 4 MB [8192x128]
    float* Ycatf = T1f;                                   // 4 MB [4096x256]
    unsigned short* T2b   = T1b;                          // 2 MB [8192x128]
    unsigned short* Xcat2 = (unsigned short*)((char*)T1b + 2097152); // 2 MB [8192x128]
    unsigned short* Ycatb = XtT;                          // 2 MB [4096x256] (XtT dead after G1)
    unsigned short* Xt2   = Xcat2 + (size_t)N * 128;      // rows 4096..8191

    // --- prep: casts/transposes -------------------------------------------
    cast2_bf16_k<<<2048, 256, 0, stream>>>(A_s, Asb, A_t, Atb, N * N / 4);
    transpose_cast_k<<<dim3(8, 128), 256, 0, stream>>>(X_s, XsT, N, 256);
    transpose_cast_k<<<dim3(8, 128), 256, 0, stream>>>(X_t, XtT, N, 256);
    transpose_cast_k<<<dim3(4, 8), 256, 0, stream>>>(W1, W1t, 256, 128);
    transpose_cast_k<<<dim3(4, 4), 256, 0, stream>>>(W2, W2t, 128, 128);
    transpose_cast_k<<<dim3(4, 4), 256, 0, stream>>>(W3, W3t, 128, 128);
    transpose_cast_k<<<dim3(4, 4), 256, 0, stream>>>(W4, W4t, 128, 128);

    // --- G1: T1 = [A_s;A_t] @ [X_s;X_t]  M=8192 N=256 K=4096, splitK=2 ----
    hipMemsetAsync(T1f, 0, 8388608, stream);
    gemm_nt<128, 128, 4, 4, EP_ATOMIC, true><<<dim3(64, 2, 2), 256, 0, stream>>>(
        Asb, Atb, XsT, XtT, 4096, 4096, 4096, 2048, T1f, nullptr, nullptr, 256, 0);
    cast_f32_bf16_k<<<2048, 256, 0, stream>>>(T1f, T1b, 8192 * 256 / 4);

    // --- G2: X1^T = relu(T1 @ W1)^T  M=8192 N=128 K=256 -------------------
    gemm_nt<64, 128, 2, 4, EP_RELU_T, false><<<dim3(128, 1, 1), 256, 0, stream>>>(
        T1b, nullptr, W1t, nullptr, 0, 256, 256, 256, nullptr, nullptr, Xcat1T, 0, 8192);

    // --- G3: T2 = [A_s;A_t] @ X1  M=8192 N=128 K=4096, splitK=4 -----------
    hipMemsetAsync(T2f, 0, 4194304, stream);
    gemm_nt<128, 128, 4, 4, EP_ATOMIC, true><<<dim3(64, 1, 4), 256, 0, stream>>>(
        Asb, Atb, Xcat1T, Xcat1T + 4096, 4096, 4096, 8192, 1024, T2f, nullptr, nullptr, 128, 0);
    cast_f32_bf16_k<<<1024, 256, 0, stream>>>(T2f, T2b, 8192 * 128 / 4);

    // --- G4: X2 = relu(T2 @ W2): rm (Xcat2) + foldT (XcatT)  M=8192 -------
    gemm_nt<64, 128, 2, 4, EP_RELU_RM_TFOLD, false><<<dim3(128, 1, 1), 256, 0, stream>>>(
        T2b, nullptr, W2t, nullptr, 0, 128, 128, 128, nullptr, Xcat2, XcatT, 128, 4096);

    // --- G9: P = Xs2 @ W3  M=4096 N=128 K=128 -----------------------------
    gemm_nt<64, 128, 2, 4, EP_BF16, false><<<dim3(64, 1, 1), 256, 0, stream>>>(
        Xcat2, nullptr, W3t, nullptr, 0, 128, 128, 128, nullptr, Pb, nullptr, 128, 0);

    // --- G10: S = exp(P @ Xt2^T): fp32 -> d_out, bf16 -> Sb  M=N=4096 K=128
    gemm_nt<128, 128, 4, 4, EP_EXP, false><<<dim3(32, 32, 1), 256, 0, stream>>>(
        Pb, nullptr, Xt2, nullptr, 0, 128, 128, 128, S_out, Sb, nullptr, 4096, 0);

    // --- G11: Ycat = S @ [Xs2|Xt2]  M=4096 N=256 K=4096, splitK=4 ---------
    hipMemsetAsync(Ycatf, 0, 4194304, stream);
    gemm_nt<128, 128, 4, 4, EP_ATOMIC, false><<<dim3(32, 2, 4), 256, 0, stream>>>(
        Sb, nullptr, XcatT, nullptr, 0, 4096, 4096, 1024, Ycatf, nullptr, nullptr, 256, 0);
    cast_f32_bf16_k<<<1024, 256, 0, stream>>>(Ycatf, Ycatb, 4096 * 256 / 4);

    // --- G12: out_s = Ys @ W4, out_t = Yt @ W4  M=4096 N=128 K=128 --------
    gemm_nt<64, 128, 2, 4, EP_F32, false><<<dim3(64, 1, 1), 256, 0, stream>>>(
        Ycatb, nullptr, W4t, nullptr, 0, 256, 128, 128, out_s, nullptr, nullptr, 128, 0);
    gemm_nt<64, 128, 2, 4, EP_F32, false><<<dim3(64, 1, 1), 256, 0, stream>>>(
        Ycatb + 128, nullptr, W4t, nullptr, 0, 256, 128, 128, out_t, nullptr, nullptr, 128, 0);
}

// Round 2
// 347.157 us; speedup vs baseline: 1.1652x; 1.1652x over previous
//
#include <hip/hip_runtime.h>
#include <stdint.h>

typedef __attribute__((ext_vector_type(4))) float f32x4;
typedef __attribute__((ext_vector_type(8))) short s16x8;

typedef const __attribute__((address_space(1))) void* gas_ptr;
typedef __attribute__((address_space(3))) void* las_ptr;

__device__ __forceinline__ unsigned short f2b(float f) {
    union { float f; unsigned u; } v; v.f = f;
    unsigned r = v.u + 0x7fffu + ((v.u >> 16) & 1u);
    return (unsigned short)(r >> 16);
}

// pack two fp32 -> one dword of two bf16 (round-half-up) via v_perm
__device__ __forceinline__ unsigned pack2(float f0, float f1) {
    union { float f; unsigned u; } a, b;
    a.f = f0; b.f = f1;
    return __builtin_amdgcn_perm(b.u + 0x8000u, a.u + 0x8000u, 0x07060302u);
}

// ---------------------------------------------------------------------------
__global__ void cast2_bf16_k(const float* __restrict__ a, unsigned short* __restrict__ da,
                             const float* __restrict__ b, unsigned short* __restrict__ db,
                             int n4) {
    int i = blockIdx.x * blockDim.x + threadIdx.x;
    int stride = gridDim.x * blockDim.x;
    for (; i < n4; i += stride) {
        float4 va = ((const float4*)a)[i];
        ushort4 pa; pa.x = f2b(va.x); pa.y = f2b(va.y); pa.z = f2b(va.z); pa.w = f2b(va.w);
        ((ushort4*)da)[i] = pa;
        float4 vb = ((const float4*)b)[i];
        ushort4 pb; pb.x = f2b(vb.x); pb.y = f2b(vb.y); pb.z = f2b(vb.z); pb.w = f2b(vb.w);
        ((ushort4*)db)[i] = pb;
    }
}

__global__ void relu_cast_k(const float* __restrict__ s, unsigned short* __restrict__ d, int n4) {
    int i = blockIdx.x * blockDim.x + threadIdx.x;
    int stride = gridDim.x * blockDim.x;
    for (; i < n4; i += stride) {
        float4 v = ((const float4*)s)[i];
        ushort4 p;
        p.x = f2b(fmaxf(v.x, 0.f)); p.y = f2b(fmaxf(v.y, 0.f));
        p.z = f2b(fmaxf(v.z, 0.f)); p.w = f2b(fmaxf(v.w, 0.f));
        ((ushort4*)d)[i] = p;
    }
}

// all four W transposes in one launch; z selects matrix
__global__ void transpose_w_k(const float* __restrict__ W1, const float* __restrict__ W2,
                              const float* __restrict__ W3, const float* __restrict__ W4,
                              unsigned short* __restrict__ W1t, unsigned short* __restrict__ W2t,
                              unsigned short* __restrict__ W3t, unsigned short* __restrict__ W4t) {
    __shared__ float tile[32][33];
    const float* src; unsigned short* dst; int R, C;
    switch (blockIdx.z) {
        case 0: src = W1; dst = W1t; R = 256; C = 128; break;
        case 1: src = W2; dst = W2t; R = 128; C = 128; break;
        case 2: src = W3; dst = W3t; R = 128; C = 128; break;
        default: src = W4; dst = W4t; R = 128; C = 128; break;
    }
    int c0 = blockIdx.x * 32, r0 = blockIdx.y * 32;
    if (r0 >= R) return;
    int tx = threadIdx.x & 31, ty = threadIdx.x >> 5;
    #pragma unroll
    for (int rr = ty; rr < 32; rr += 8)
        tile[rr][tx] = src[(size_t)(r0 + rr) * C + c0 + tx];
    __syncthreads();
    #pragma unroll
    for (int rr = ty; rr < 32; rr += 8)
        dst[(size_t)(c0 + rr) * R + r0 + tx] = f2b(tile[tx][rr]);
}

// ---------------------------------------------------------------------------
// NT bf16 GEMM: C[m,n] = sum_k A[m,k]*B[n,k]. 256 thr = 4 waves (2x2).
enum { EP_BF16 = 0,   // bf16 row-major -> Cb
       EP_T = 1,      // bf16 transposed -> Ct[n][m], ldct
       EP_TFOLD = 2,  // bf16 transposed with graph fold: Ct[n + 128*(m>=4096)][m&4095]
       EP_EXP = 3,    // exp: fp32 rm -> Cf AND bf16 rm -> Cb
       EP_OUT2 = 4 }; // atomicAdd fp32 into out_s/out_t halves of Cf

template<int BM, int BN, int FM, int FN, int EPI>
__global__ void __launch_bounds__(256)
gemm_nt(const unsigned short* __restrict__ A, const unsigned short* __restrict__ B,
        int lda, int ldb, int kchunk,
        float* __restrict__ Cf, unsigned short* __restrict__ Cb,
        unsigned short* __restrict__ Ct, int ldc, int ldct)
{
    static_assert(BM == 32 * FM * 2 || BM == 32 * FM, "tile");
    __shared__ __align__(16) short As[BM * 32];
    __shared__ __align__(16) short Bs[BN * 32];

    const int t = threadIdx.x;
    const int lane = t & 63;
    const int w = t >> 6;
    const int wr = w >> 1, wc = w & 1;
    const int m0 = blockIdx.x * BM;
    const int n0 = blockIdx.y * BN;
    const int k0 = blockIdx.z * kchunk;

    f32x4 acc[FM][FN];
    #pragma unroll
    for (int i = 0; i < FM; i++)
        #pragma unroll
        for (int j = 0; j < FN; j++) acc[i][j] = (f32x4){0.f, 0.f, 0.f, 0.f};

    const int KT = kchunk >> 5;
    const int mrow = lane & 15;
    const int q8 = (lane >> 4) << 3;

    for (int kt = 0; kt < KT; ++kt) {
        const int kk = k0 + (kt << 5);
        #pragma unroll
        for (int idx = t; idx < BM * 4; idx += 256) {
            const unsigned short* g = A + (size_t)(m0 + (idx >> 2)) * lda + kk + ((idx & 3) << 3);
            __builtin_amdgcn_global_load_lds((gas_ptr)g, (las_ptr)(As + idx * 8), 16, 0, 0);
        }
        #pragma unroll
        for (int idx = t; idx < BN * 4; idx += 256) {
            const unsigned short* g = B + (size_t)(n0 + (idx >> 2)) * ldb + kk + ((idx & 3) << 3);
            __builtin_amdgcn_global_load_lds((gas_ptr)g, (las_ptr)(Bs + idx * 8), 16, 0, 0);
        }
        __syncthreads();

        s16x8 af[FM], bfr[FN];
        #pragma unroll
        for (int i = 0; i < FM; i++)
            af[i] = *(const s16x8*)(const void*)(As + (wr * FM * 16 + i * 16 + mrow) * 32 + q8);
        #pragma unroll
        for (int j = 0; j < FN; j++)
            bfr[j] = *(const s16x8*)(const void*)(Bs + (wc * FN * 16 + j * 16 + mrow) * 32 + q8);
        #pragma unroll
        for (int i = 0; i < FM; i++)
            #pragma unroll
            for (int j = 0; j < FN; j++)
                acc[i][j] = __builtin_amdgcn_mfma_f32_16x16x32_bf16(af[i], bfr[j], acc[i][j], 0, 0, 0);
        __syncthreads();
    }

    const int cn = lane & 15;
    const int q4 = (lane >> 4) << 2;
    #pragma unroll
    for (int i = 0; i < FM; i++) {
        const int mb = m0 + wr * FM * 16 + i * 16 + q4;
        #pragma unroll
        for (int j = 0; j < FN; j++) {
            const int nn = n0 + wc * FN * 16 + j * 16 + cn;
            if constexpr (EPI == EP_BF16) {
                #pragma unroll
                for (int r = 0; r < 4; r++)
                    Cb[(size_t)(mb + r) * ldc + nn] = f2b(acc[i][j][r]);
            } else if constexpr (EPI == EP_T) {
                ushort4 p;
                p.x = f2b(acc[i][j][0]); p.y = f2b(acc[i][j][1]);
                p.z = f2b(acc[i][j][2]); p.w = f2b(acc[i][j][3]);
                *(ushort4*)(void*)(Ct + (size_t)nn * ldct + mb) = p;
            } else if constexpr (EPI == EP_TFOLD) {
                ushort4 p;
                p.x = f2b(acc[i][j][0]); p.y = f2b(acc[i][j][1]);
                p.z = f2b(acc[i][j][2]); p.w = f2b(acc[i][j][3]);
                const int trow = nn + ((mb >> 12) << 7);
                *(ushort4*)(void*)(Ct + (size_t)trow * ldct + (mb & 4095)) = p;
            } else if constexpr (EPI == EP_EXP) {
                #pragma unroll
                for (int r = 0; r < 4; r++) {
                    float v = __expf(acc[i][j][r]);
                    Cf[(size_t)(mb + r) * ldc + nn] = v;
                    Cb[(size_t)(mb + r) * ldc + nn] = f2b(v);
                }
            } else if constexpr (EPI == EP_OUT2) {
                const size_t off = (size_t)(nn & 127) + ((nn >> 7) ? (size_t)4096 * 128 : 0);
                #pragma unroll
                for (int r = 0; r < 4; r++)
                    atomicAdd(Cf + (size_t)(mb + r) * 128 + off, acc[i][j][r]);
            }
        }
    }
}

// ---------------------------------------------------------------------------
// fp32-A NT GEMM: C[m,n] += sum_k A_f32[m,k]*B_bf16[n,k]; split-K atomic fp32.
// A staged fp32 in LDS with XOR(row&7) group swizzle (2-way banks), packed to
// bf16 in-register via v_perm. BM=BN=128, FM=FN=4. DUAL: m>=Mhalf -> A2/B2.
__global__ void __launch_bounds__(256)
gemm_a32_nt(const float* __restrict__ A, const float* __restrict__ A2,
            const unsigned short* __restrict__ B, const unsigned short* __restrict__ B2,
            int Mhalf, int lda, int ldb, int kchunk, float* __restrict__ Cf, int ldc)
{
    __shared__ __align__(16) float As[128 * 32];   // 16 KB
    __shared__ __align__(16) short Bs[128 * 32];   // 8 KB

    const int t = threadIdx.x;
    const int lane = t & 63;
    const int w = t >> 6;
    const int wr = w >> 1, wc = w & 1;
    const int m0 = blockIdx.x * 128;
    const int n0 = blockIdx.y * 128;
    const int k0 = blockIdx.z * kchunk;

    const float* Ap = A;
    const unsigned short* Bp = B;
    int am0 = m0;
    if (m0 >= Mhalf) { Ap = A2; Bp = B2; am0 = m0 - Mhalf; }

    f32x4 acc[4][4];
    #pragma unroll
    for (int i = 0; i < 4; i++)
        #pragma unroll
        for (int j = 0; j < 4; j++) acc[i][j] = (f32x4){0.f, 0.f, 0.f, 0.f};

    const int KT = kchunk >> 5;
    const int mrow = lane & 15;
    const int q8 = (lane >> 4) << 3;
    const int q2 = (lane >> 4) << 1;

    for (int kt = 0; kt < KT; ++kt) {
        const int kk = k0 + (kt << 5);
        #pragma unroll
        for (int it = 0; it < 4; ++it) {          // 1024 A slots of 16B
            int idx = it * 256 + t;
            int row = idx >> 3, grp = idx & 7;
            const float* g = Ap + (size_t)(am0 + row) * lda + kk + ((grp ^ (row & 7)) << 2);
            __builtin_amdgcn_global_load_lds((gas_ptr)g, (las_ptr)(As + idx * 4), 16, 0, 0);
        }
        #pragma unroll
        for (int it = 0; it < 2; ++it) {          // 512 B slots
            int idx = it * 256 + t;
            const unsigned short* g = Bp + (size_t)(n0 + (idx >> 2)) * ldb + kk + ((idx & 3) << 3);
            __builtin_amdgcn_global_load_lds((gas_ptr)g, (las_ptr)(Bs + idx * 8), 16, 0, 0);
        }
        __syncthreads();

        s16x8 af[4], bfr[4];
        #pragma unroll
        for (int i = 0; i < 4; i++) {
            const int r = wr * 64 + i * 16 + mrow;
            const f32x4 lo = *(const f32x4*)(const void*)(As + r * 32 + ((q2 ^ (r & 7)) << 2));
            const f32x4 hi = *(const f32x4*)(const void*)(As + r * 32 + (((q2 | 1) ^ (r & 7)) << 2));
            union { s16x8 v; unsigned u[4]; } pk;
            pk.u[0] = pack2(lo[0], lo[1]); pk.u[1] = pack2(lo[2], lo[3]);
            pk.u[2] = pack2(hi[0], hi[1]); pk.u[3] = pack2(hi[2], hi[3]);
            af[i] = pk.v;
        }
        #pragma unroll
        for (int j = 0; j < 4; j++)
            bfr[j] = *(const s16x8*)(const void*)(Bs + (wc * 64 + j * 16 + mrow) * 32 + q8);
        #pragma unroll
        for (int i = 0; i < 4; i++)
            #pragma unroll
            for (int j = 0; j < 4; j++)
                acc[i][j] = __builtin_amdgcn_mfma_f32_16x16x32_bf16(af[i], bfr[j], acc[i][j], 0, 0, 0);
        __syncthreads();
    }

    const int cn = lane & 15;
    const int q4 = (lane >> 4) << 2;
    #pragma unroll
    for (int i = 0; i < 4; i++) {
        const int mb = m0 + wr * 64 + i * 16 + q4;
        #pragma unroll
        for (int j = 0; j < 4; j++) {
            const int nn = n0 + wc * 64 + j * 16 + cn;
            #pragma unroll
            for (int r = 0; r < 4; r++)
                atomicAdd(Cf + (size_t)(mb + r) * ldc + nn, acc[i][j][r]);
        }
    }
}

// ---------------------------------------------------------------------------
extern "C" void kernel_launch(void* const* d_in, const int* in_sizes, int n_in,
                              void* d_out, int out_size, void* d_ws, size_t ws_size,
                              hipStream_t stream) {
    const int N = 4096;
    const float* A_s = (const float*)d_in[0];
    const float* X_s = (const float*)d_in[1];
    const float* A_t = (const float*)d_in[2];
    const float* X_t = (const float*)d_in[3];
    const float* W1  = (const float*)d_in[4];
    const float* W2  = (const float*)d_in[5];
    const float* W3  = (const float*)d_in[6];
    const float* W4  = (const float*)d_in[7];

    float* out   = (float*)d_out;
    float* S_out = out + (size_t)2 * N * 128;

    char* ws = (char*)d_ws;
    unsigned short* Xcatb = (unsigned short*)(ws + 0);          // 4 MB [8192x256]
    unsigned short* W1t   = (unsigned short*)(ws + 4194304);    // [128x256]
    unsigned short* W2t   = (unsigned short*)(ws + 4259840);    // [128x128]
    unsigned short* W3t   = (unsigned short*)(ws + 4292608);
    unsigned short* W4t   = (unsigned short*)(ws + 4325376);
    unsigned short* Y1T   = (unsigned short*)(ws + 4718592);    // 2 MB [128x8192] (also Y2T)
    float*          Pf    = (float*)(ws + 7340032);             // 4 MB [8192x128] f32 partials
    unsigned short* X1b   = (unsigned short*)(ws + 11534336);   // 2 MB [8192x128]
    unsigned short* X2b   = (unsigned short*)(ws + 13631488);   // 2 MB [8192x128]
    unsigned short* Pb    = (unsigned short*)(ws + 15728640);   // 1 MB [4096x128]
    unsigned short* ZcatT = (unsigned short*)(ws + 16777216);   // 2 MB [256x4096]
    unsigned short* Sb    = (unsigned short*)(ws + 18874368);   // 32 MB [4096x4096]
    unsigned short* Xt2b  = X2b + (size_t)N * 128;

    // prep: X cast (rm) + W transposes
    cast2_bf16_k<<<512, 256, 0, stream>>>(X_s, Xcatb, X_t, Xcatb + (size_t)N * 256, N * 256 / 4);
    transpose_w_k<<<dim3(4, 8, 4), 256, 0, stream>>>(W1, W2, W3, W4, W1t, W2t, W3t, W4t);

    // Y1 = Xcat @ W1, transposed store [128 x 8192]   M=8192 K=256 N=128
    gemm_nt<32, 128, 1, 4, EP_T><<<dim3(256, 1, 1), 256, 0, stream>>>(
        Xcatb, W1t, 256, 256, 256, nullptr, nullptr, Y1T, 0, 8192);

    // X1 = relu(Acat @ Y1)   M=8192 N=128 K=4096 splitK=8, A fp32
    hipMemsetAsync(Pf, 0, 4194304, stream);
    gemm_a32_nt<<<dim3(64, 1, 8), 256, 0, stream>>>(
        A_s, A_t, Y1T, Y1T + 4096, 4096, 4096, 8192, 512, Pf, 128);
    relu_cast_k<<<1024, 256, 0, stream>>>(Pf, X1b, 8192 * 128 / 4);

    // Y2 = X1 @ W2, transposed store   M=8192 K=128 N=128
    gemm_nt<32, 128, 1, 4, EP_T><<<dim3(256, 1, 1), 256, 0, stream>>>(
        X1b, W2t, 128, 128, 128, nullptr, nullptr, Y1T, 0, 8192);

    // X2 = relu(Acat @ Y2)
    hipMemsetAsync(Pf, 0, 4194304, stream);
    gemm_a32_nt<<<dim3(64, 1, 8), 256, 0, stream>>>(
        A_s, A_t, Y1T, Y1T + 4096, 4096, 4096, 8192, 512, Pf, 128);
    relu_cast_k<<<1024, 256, 0, stream>>>(Pf, X2b, 8192 * 128 / 4);

    // P = Xs2 @ W3  (rm bf16)   M=4096 K=128 N=128
    gemm_nt<32, 128, 1, 4, EP_BF16><<<dim3(128, 1, 1), 256, 0, stream>>>(
        X2b, W3t, 128, 128, 128, nullptr, Pb, nullptr, 128, 0);

    // Zcat^T = (Xcat2 @ W4)^T folded [256 x 4096]   M=8192 K=128 N=128
    gemm_nt<32, 128, 1, 4, EP_TFOLD><<<dim3(256, 1, 1), 256, 0, stream>>>(
        X2b, W4t, 128, 128, 128, nullptr, nullptr, ZcatT, 0, 4096);

    // S = exp(P @ Xt2^T): fp32 -> d_out, bf16 -> Sb   M=N=4096 K=128
    gemm_nt<128, 128, 4, 4, EP_EXP><<<dim3(32, 32, 1), 256, 0, stream>>>(
        Pb, Xt2b, 128, 128, 128, S_out, Sb, nullptr, 4096, 0);

    // out = S @ Zcat  (atomic fp32 into out_s/out_t)   M=4096 N=256 K=4096 splitK=8
    hipMemsetAsync(out, 0, (size_t)2 * N * 128 * 4, stream);
    gemm_nt<128, 128, 4, 4, EP_OUT2><<<dim3(32, 2, 8), 256, 0, stream>>>(
        Sb, ZcatT, 4096, 4096, 512, out, nullptr, nullptr, 256, 0);
}